// Round 1
// baseline (36.988 us; speedup 1.0000x reference)
//
#include <hip/hip_runtime.h>

// Edgenet: 4-channel fixed 3x3 Sobel-family stencil on [64,1,512,512] f32,
// edge = (sum_c |conv_c|) > 0 ? 1 : 0, output int32 [64,512,512].
//
// Memory-bound: 64 MiB in + 64 MiB out. One thread -> 4 consecutive x pixels:
// 3x float4 row loads + 6 halo scalars, 1x int4 store.

#define IMG_W 512
#define IMG_H 512

__global__ __launch_bounds__(256) void edgenet_kernel(
    const float* __restrict__ in, int* __restrict__ out, int total_quads) {
  int idx = blockIdx.x * blockDim.x + threadIdx.x;
  if (idx >= total_quads) return;

  // idx enumerates quads in output order: b * (H*W/4) + y * (W/4) + xq
  int xq = idx & (IMG_W / 4 - 1);       // 0..127
  int y  = (idx >> 7) & (IMG_H - 1);    // 0..511
  int b  = idx >> 16;                   // batch
  int x  = xq << 2;

  const float* img = in + (size_t)b * (IMG_H * IMG_W);

  float t[6], mrow[6], bo[6];
  auto loadrow = [&](int yy, float* v) {
    if (yy < 0 || yy >= IMG_H) {
      v[0] = v[1] = v[2] = v[3] = v[4] = v[5] = 0.f;
      return;
    }
    const float* row = img + yy * IMG_W;
    float4 mid = *reinterpret_cast<const float4*>(row + x);
    v[0] = (x > 0) ? row[x - 1] : 0.f;
    v[1] = mid.x; v[2] = mid.y; v[3] = mid.z; v[4] = mid.w;
    v[5] = (x + 4 < IMG_W) ? row[x + 4] : 0.f;
  };
  loadrow(y - 1, t);
  loadrow(y,     mrow);
  loadrow(y + 1, bo);

  int res[4];
#pragma unroll
  for (int j = 0; j < 4; ++j) {
    float t0 = t[j],    t1 = t[j + 1],    t2 = t[j + 2];
    float m0 = mrow[j],                   m2 = mrow[j + 2];
    float b0 = bo[j],   b1 = bo[j + 1],   b2 = bo[j + 2];
    // cross-correlation with the 4 fixed kernels
    float tx = (b0 - t0) + 2.f * (b1 - t1) + (b2 - t2);            // f_x
    float ty = (t2 - t0) + 2.f * (m2 - m0) + (b2 - b0);            // f_y
    float d1 = -2.f * t0 - t1 - m0 + m2 + b1 + 2.f * b2;           // f_tl_br
    float d2 = -t1 - 2.f * t2 + m0 - m2 + 2.f * b0 + b1;           // f_tr_bl
    float e = fabsf(tx) + fabsf(ty) + fabsf(d1) + fabsf(d2);
    res[j] = (e > 0.f) ? 1 : 0;
  }
  int4 o;
  o.x = res[0]; o.y = res[1]; o.z = res[2]; o.w = res[3];
  *reinterpret_cast<int4*>(out + (size_t)idx * 4) = o;
}

extern "C" void kernel_launch(void* const* d_in, const int* in_sizes, int n_in,
                              void* d_out, int out_size, void* d_ws, size_t ws_size,
                              hipStream_t stream) {
  const float* lab = (const float*)d_in[0];
  int* out = (int*)d_out;
  // 64 * 512 * 512 / 4 quads
  int total_quads = out_size / 4;
  int threads = 256;
  int blocks = (total_quads + threads - 1) / threads;
  edgenet_kernel<<<blocks, threads, 0, stream>>>(lab, out, total_quads);
}

// Round 2
// 36.896 us; speedup vs baseline: 1.0025x; 1.0025x over previous
//
#include <hip/hip_runtime.h>

// Edgenet: 4-channel fixed 3x3 Sobel-family stencil on [64,1,512,512] f32,
// edge = (sum_c |conv_c|) > 0 ? 1 : 0, output int32 [64,512,512].
//
// Memory-bound: 64 MiB in + 64 MiB out. One thread -> 4 consecutive x pixels.
// Halo values come from neighbor lanes via shuffle (lane stride = 16B), so
// per thread: 3x float4 row loads + 1 predicated scalar halo load per row
// (2 active lanes/wave) + 1 int4 store. Cuts L1 transactions ~3x vs the
// scalar-halo version (which ran at 3.3 TB/s, 41% peak).

#define IMG_W 512
#define IMG_H 512

__global__ __launch_bounds__(256) void edgenet_kernel(
    const float* __restrict__ in, int* __restrict__ out) {
  int idx  = blockIdx.x * 256 + threadIdx.x;
  int lane = threadIdx.x & 63;
  int xq = idx & (IMG_W / 4 - 1);       // 0..127
  int y  = (idx >> 7) & (IMG_H - 1);    // 0..511 (wave-uniform: low 6 bits are xq)
  int b  = idx >> 16;                   // batch
  int x  = xq << 2;

  const float* img = in + (size_t)b * (IMG_H * IMG_W);

  float v[3][6];
#pragma unroll
  for (int r = 0; r < 3; ++r) {
    int yy = y + r - 1;
    if (yy < 0 || yy >= IMG_H) {        // wave-uniform branch (y uniform per wave)
      v[r][0] = v[r][1] = v[r][2] = v[r][3] = v[r][4] = v[r][5] = 0.f;
      continue;
    }
    const float* row = img + yy * IMG_W;
    float4 mid = *reinterpret_cast<const float4*>(row + x);
    // halos from neighbor lanes (lane i holds pixels x..x+3, stride 16B)
    float left  = __shfl_up(mid.w, 1);
    float right = __shfl_down(mid.x, 1);
    // wave-boundary lanes: one predicated load covers both (2 active lanes)
    if (lane == 0 || lane == 63) {
      bool is_l = (lane == 0);
      int  hx   = is_l ? x - 1 : x + 4;
      bool ok   = is_l ? (x > 0) : (x + 4 < IMG_W);
      float h   = ok ? row[hx] : 0.f;
      if (is_l) left = h; else right = h;
    }
    v[r][0] = left;  v[r][1] = mid.x; v[r][2] = mid.y;
    v[r][3] = mid.z; v[r][4] = mid.w; v[r][5] = right;
  }

  int res[4];
#pragma unroll
  for (int j = 0; j < 4; ++j) {
    float t0 = v[0][j], t1 = v[0][j + 1], t2 = v[0][j + 2];
    float m0 = v[1][j],                   m2 = v[1][j + 2];
    float b0 = v[2][j], b1 = v[2][j + 1], b2 = v[2][j + 2];
    float tx = (b0 - t0) + 2.f * (b1 - t1) + (b2 - t2);            // f_x
    float ty = (t2 - t0) + 2.f * (m2 - m0) + (b2 - b0);            // f_y
    float d1 = -2.f * t0 - t1 - m0 + m2 + b1 + 2.f * b2;           // f_tl_br
    float d2 = -t1 - 2.f * t2 + m0 - m2 + 2.f * b0 + b1;           // f_tr_bl
    float e = fabsf(tx) + fabsf(ty) + fabsf(d1) + fabsf(d2);
    res[j] = (e > 0.f) ? 1 : 0;
  }
  int4 o;
  o.x = res[0]; o.y = res[1]; o.z = res[2]; o.w = res[3];
  *reinterpret_cast<int4*>(out + (size_t)idx * 4) = o;
}

extern "C" void kernel_launch(void* const* d_in, const int* in_sizes, int n_in,
                              void* d_out, int out_size, void* d_ws, size_t ws_size,
                              hipStream_t stream) {
  const float* lab = (const float*)d_in[0];
  int* out = (int*)d_out;
  int total_quads = out_size / 4;       // 64*512*512/4
  int threads = 256;
  int blocks = total_quads / threads;   // exact: 16384
  edgenet_kernel<<<blocks, threads, 0, stream>>>(lab, out);
}

// Round 3
// 29.479 us; speedup vs baseline: 1.2547x; 1.2516x over previous
//
#include <hip/hip_runtime.h>

// Edgenet: 4-channel fixed 3x3 Sobel-family stencil on [64,1,512,512] f32,
// edge = (sum_c |conv_c|) > 0 ? 1 : 0, output int32 [64,512,512].
//
// Round-3 structure: one wave owns a full 512-px-wide strip of R=8 rows.
// Lane l holds pixels [8l, 8l+7] (two float4 loads/row); left/right halos
// come from neighbor lanes via shuffle, image edges are implicit zeros --
// zero extra halo loads. Rows slide through a 4-slot register window with
// loads issued 2 iterations ahead (software pipeline). 4096 waves total
// (1024 blocks x 4 waves), all resident: no dispatch-rate limit, deep ILP.

#define IMG_W 512
#define IMG_H 512
#define R_ROWS 8

struct Row {
  float4 lo, hi;   // pixels 8l..8l+3, 8l+4..8l+7
  float lft, rgt;  // halo pixels 8l-1, 8l+8
};

__device__ __forceinline__ float rget(const Row& r, int k) {
  // k is compile-time constant after full unroll; switch folds away.
  switch (k) {
    case 0: return r.lft;
    case 1: return r.lo.x; case 2: return r.lo.y;
    case 3: return r.lo.z; case 4: return r.lo.w;
    case 5: return r.hi.x; case 6: return r.hi.y;
    case 7: return r.hi.z; case 8: return r.hi.w;
    default: return r.rgt;
  }
}

__device__ __forceinline__ void loadrow(Row& r, const float* img, int yy, int px) {
  if ((unsigned)yy < (unsigned)IMG_H) {   // wave-uniform branch
    const float* p = img + yy * IMG_W + px;
    r.lo = *reinterpret_cast<const float4*>(p);
    r.hi = *reinterpret_cast<const float4*>(p + 4);
  } else {
    r.lo = make_float4(0.f, 0.f, 0.f, 0.f);
    r.hi = make_float4(0.f, 0.f, 0.f, 0.f);
  }
}

__device__ __forceinline__ void finishrow(Row& r, int lane) {
  // waits (vmcnt) happen here at first use of the loaded data
  float lf = __shfl_up(r.hi.w, 1);
  float rt = __shfl_down(r.lo.x, 1);
  r.lft = (lane == 0)  ? 0.f : lf;   // pixel -1  -> 0 (image edge)
  r.rgt = (lane == 63) ? 0.f : rt;   // pixel 512 -> 0
}

__device__ __forceinline__ void compute_store(const Row& T, const Row& M,
                                              const Row& B, int* orow) {
  int res[8];
#pragma unroll
  for (int j = 0; j < 8; ++j) {
    float t0 = rget(T, j), t1 = rget(T, j + 1), t2 = rget(T, j + 2);
    float m0 = rget(M, j),                      m2 = rget(M, j + 2);
    float b0 = rget(B, j), b1 = rget(B, j + 1), b2 = rget(B, j + 2);
    float tx = (b0 - t0) + 2.f * (b1 - t1) + (b2 - t2);            // f_x
    float ty = (t2 - t0) + 2.f * (m2 - m0) + (b2 - b0);            // f_y
    float d1 = -2.f * t0 - t1 - m0 + m2 + b1 + 2.f * b2;           // f_tl_br
    float d2 = -t1 - 2.f * t2 + m0 - m2 + 2.f * b0 + b1;           // f_tr_bl
    float e = fabsf(tx) + fabsf(ty) + fabsf(d1) + fabsf(d2);
    res[j] = (e > 0.f) ? 1 : 0;
  }
  *reinterpret_cast<int4*>(orow)     = make_int4(res[0], res[1], res[2], res[3]);
  *reinterpret_cast<int4*>(orow + 4) = make_int4(res[4], res[5], res[6], res[7]);
}

__global__ __launch_bounds__(256) void edgenet_kernel(
    const float* __restrict__ in, int* __restrict__ out) {
  const int lane = threadIdx.x & 63;
  const int wid  = threadIdx.x >> 6;                 // 0..3
  const int b    = blockIdx.x >> 4;                  // image index
  const int y0   = ((blockIdx.x & 15) << 5) + (wid << 3);  // strip start row
  const int px   = lane << 3;                        // first pixel of lane

  const float* img = in + (size_t)b * (IMG_H * IMG_W);
  int* orow = out + ((size_t)b * IMG_H + y0) * IMG_W + px;

  Row s[4];
  // prologue: rows y0-1 .. y0+2 in flight
  loadrow(s[0], img, y0 - 1, px);
  loadrow(s[1], img, y0,     px);
  loadrow(s[2], img, y0 + 1, px);
  loadrow(s[3], img, y0 + 2, px);
  finishrow(s[0], lane);
  finishrow(s[1], lane);

#pragma unroll
  for (int i = 0; i < R_ROWS; ++i) {
    finishrow(s[(i + 2) & 3], lane);                 // row y0+i+1 ready
    compute_store(s[i & 3], s[(i + 1) & 3], s[(i + 2) & 3],
                  orow + i * IMG_W);
    if (i < R_ROWS - 2)                              // rows y0+3 .. y0+8
      loadrow(s[i & 3], img, y0 + i + 3, px);        // slot y0+i-1 is dead
  }
}

extern "C" void kernel_launch(void* const* d_in, const int* in_sizes, int n_in,
                              void* d_out, int out_size, void* d_ws, size_t ws_size,
                              hipStream_t stream) {
  const float* lab = (const float*)d_in[0];
  int* out = (int*)d_out;
  // 64 images x 16 blocks per image (each block: 4 waves x 8-row strips = 32 rows)
  int blocks = 64 * (IMG_H / (4 * R_ROWS));          // 1024
  edgenet_kernel<<<blocks, 256, 0, stream>>>(lab, out);
}